// Round 1
// 87.493 us; speedup vs baseline: 1.0308x; 1.0308x over previous
//
#include <hip/hip_runtime.h>
#include <math.h>

typedef short bf16x8 __attribute__((ext_vector_type(8)));
typedef float f32x4 __attribute__((ext_vector_type(4)));

#define KP 800        // 784 padded to 25*32
#define AS_LD 808     // LDS A row stride (shorts): 1616 B, 16B-aligned
#define HS_LD 260     // LDS H row stride (floats): 1040 B, 16B-aligned

// ---- fp32 -> bf16 (RNE) ---------------------------------------------------
__device__ __forceinline__ unsigned short f2bf(float f) {
    unsigned int u = __float_as_uint(f);
    u = (u + 0x7FFFu + ((u >> 16) & 1u)) >> 16;
    return (unsigned short)u;
}

// ---------------------------------------------------------------------------
// W1 [256,784] fp32 -> bf16, K-padded to [256,800]. Kept as a separate tiny
// kernel: bf16-in-global HALVES phase-2 L2 traffic (100 MB vs 200 MB for
// direct f32 reads across 256 blocks), which is phase 2's binding resource.
// ---------------------------------------------------------------------------
__global__ __launch_bounds__(256) void w1cvt_kernel(
        const float* __restrict__ W1, unsigned short* __restrict__ w1bf) {
    const int id = blockIdx.x * 256 + threadIdx.x;  // 0 .. 204799
    const int r = id / KP;
    const int c = id - r * KP;
    w1bf[id] = f2bf((c < 784) ? W1[r * 784 + c] : 0.f);
}

// ---------------------------------------------------------------------------
// Fully fused kernel. Block = 1024 threads (16 waves, 4 waves/SIMD), 16 rows.
// Phase 1: quanv sims -> bf16 A-tile in LDS. 3-4 sims/thread with next-sim
//          pixel prefetch; encoder as 24-mul product; Z via 2S-1 (32 fma);
//          packed bf16 store via v_cvt_pk_bf16_f32.
// Phase 2: 16 waves x 16 output cols, 1 MFMA chain each; b-frags b128 direct
//          from global bf16 W1 (L2-resident, depth-2 prefetch).
// Epilogue: relu+bias H-tile -> LDS; layer2 (64 lanes/row, float4 each) +
//          butterfly reduce + log_softmax.
// ---------------------------------------------------------------------------

__device__ __forceinline__ void ry_gate(float a[16], int bitpos, float c, float s) {
    const int mask = 1 << bitpos;
#pragma unroll
    for (int i = 0; i < 16; ++i) {
        if (!(i & mask)) {
            const int j = i | mask;
            const float a0 = a[i], a1 = a[j];
            a[i] = c * a0 - s * a1;
            a[j] = s * a0 + c * a1;
        }
    }
}

__device__ __forceinline__ void cnot_gate(float a[16], int cbit, int tbit) {
    const int cmask = 1 << cbit, tmask = 1 << tbit;
#pragma unroll
    for (int i = 0; i < 16; ++i) {
        if ((i & cmask) && !(i & tmask)) {
            const int j = i | tmask;
            const float tmp = a[i];
            a[i] = a[j];
            a[j] = tmp;
        }
    }
}

__global__ __launch_bounds__(1024) void fused_kernel(
        const float* __restrict__ x, const float* __restrict__ var_angles,
        const unsigned short* __restrict__ w1bf, const float* __restrict__ b1,
        const float* __restrict__ W2, const float* __restrict__ b2,
        float* __restrict__ out) {
    __shared__ unsigned short As[16][AS_LD];   // 25,856 B
    __shared__ float Hs[16][HS_LD];            // 16,640 B
    __shared__ float W2s[2560];                // 10,240 B
    __shared__ float b1s[256];
    __shared__ float b2s[12];

    const int tid = threadIdx.x;
    const int r0 = blockIdx.x * 16;

    // ---- side staging of layer-2 params (overlaps phase 1) ----
    for (int idx = tid; idx < 2560; idx += 1024) W2s[idx] = W2[idx];
    if (tid < 256) b1s[tid] = b1[tid];
    if (tid < 10) b2s[tid] = b2[tid];

    // ---- K-pad zeroing: rows 0..15, cols 784..799 (NaN*0=NaN guard) ----
    if (tid < 64) {
        const ushort4 zz = {0, 0, 0, 0};
        *(ushort4*)&As[tid >> 2][784 + (tid & 3) * 4] = zz;
    }

    // ---- phase 1: quanv sims into LDS A-tile ----
    float vvc[8], vvs[8];
#pragma unroll
    for (int ii = 0; ii < 8; ++ii) {
        const float h = 0.5f * var_angles[ii];
        vvs[ii] = __sinf(h);
        vvc[ii] = __cosf(h);
    }

#define PIXLOAD(II, T, B) { \
        const int lr_ = (II) / 196; \
        const int p_  = (II) - lr_ * 196; \
        const int pr_ = p_ / 14; \
        const int pc_ = p_ - pr_ * 14; \
        const float* img_ = x + (size_t)(r0 + lr_) * 784 + (2 * pr_) * 28 + 2 * pc_; \
        T = *(const float2*)(img_); \
        B = *(const float2*)(img_ + 28); \
    }

    int i = tid;                      // 3136 sims, 1024 threads: 3-4 each
    float2 top, bot;
    PIXLOAD(i, top, bot)
    for (;;) {
        const int inxt = i + 1024;
        const bool more = (inxt < 16 * 196);
        float2 topn, botn;
        if (more) PIXLOAD(inxt, topn, botn)   // prefetch: hides HBM latency

        const int lr = i / 196;
        const int p  = i - lr * 196;

        float c[4], s[4];
        {
            const float th[4] = {top.x, top.y, bot.x, bot.y};
#pragma unroll
            for (int w = 0; w < 4; ++w) {
                const float h = 0.5f * th[w];
                s[w] = __sinf(h);
                c[w] = __cosf(h);
            }
        }

        // encoder |0000> -> product state: 8 + 16 muls
        const float p01[4] = {c[0] * c[1], c[0] * s[1], s[0] * c[1], s[0] * s[1]};
        const float p23[4] = {c[2] * c[3], c[2] * s[3], s[2] * c[3], s[2] * s[3]};
        float a[16];
#pragma unroll
        for (int k = 0; k < 16; ++k) a[k] = p01[k >> 2] * p23[k & 3];

#pragma unroll
        for (int d = 0; d < 2; ++d) {
#pragma unroll
            for (int w = 0; w < 4; ++w)
                ry_gate(a, 3 - w, vvc[d * 4 + w], vvs[d * 4 + w]);
            cnot_gate(a, 3, 2);  // pure register renames after unroll
            cnot_gate(a, 2, 1);
            cnot_gate(a, 1, 0);
            cnot_gate(a, 0, 3);
        }

        // <Z_w> = 2*P(bit clear) - 1 : 32 fma + 4 fma (was 16 mul + 64 add)
        float S0 = 0.f, S1 = 0.f, S2 = 0.f, S3 = 0.f;
#pragma unroll
        for (int k = 0; k < 16; ++k) {
            if (!(k & 8)) S0 = __builtin_fmaf(a[k], a[k], S0);
            if (!(k & 4)) S1 = __builtin_fmaf(a[k], a[k], S1);
            if (!(k & 2)) S2 = __builtin_fmaf(a[k], a[k], S2);
            if (!(k & 1)) S3 = __builtin_fmaf(a[k], a[k], S3);
        }
        const float z0 = __builtin_fmaf(2.f, S0, -1.f);
        const float z1 = __builtin_fmaf(2.f, S1, -1.f);
        const float z2 = __builtin_fmaf(2.f, S2, -1.f);
        const float z3 = __builtin_fmaf(2.f, S3, -1.f);

        // packed RNE bf16 convert: 2 instrs (was ~20)
        unsigned int lo, hi;
        asm("v_cvt_pk_bf16_f32 %0, %1, %2" : "=v"(lo) : "v"(z0), "v"(z1));
        asm("v_cvt_pk_bf16_f32 %0, %1, %2" : "=v"(hi) : "v"(z2), "v"(z3));
        uint2 hv;
        hv.x = lo;
        hv.y = hi;
        *(uint2*)&As[lr][p * 4] = hv;

        if (!more) break;
        i = inxt;
        top = topn;
        bot = botn;
    }
    __syncthreads();

    // ---- phase 2: barrier-free MFMA K-loop, 16 waves x 16 cols ----
    const int lane = tid & 63;
    const int wv = tid >> 6;      // 0..15: wave owns cols [wv*16, wv*16+16)
    const int q = lane >> 4;
    const int lm = lane & 15;
    const int n0 = wv * 16;

    const unsigned short* pB = w1bf + (size_t)(n0 + lm) * KP + q * 8;

    f32x4 acc = (f32x4)(0.f);
    bf16x8 bcur = *(const bf16x8*)(pB);
    bf16x8 bnxt = *(const bf16x8*)(pB + 32);

    for (int k0 = 0; k0 < KP; k0 += 32) {
        const bf16x8 afrag = *(const bf16x8*)&As[lm][k0 + q * 8];
        acc = __builtin_amdgcn_mfma_f32_16x16x32_bf16(afrag, bcur, acc, 0, 0, 0);
        bcur = bnxt;
        if (k0 + 64 < KP) {  // depth-2 prefetch (L2-hit ~200-400 cyc)
            bnxt = *(const bf16x8*)(pB + k0 + 64);
        }
    }

    // ---- epilogue: H-tile (bias+relu) to LDS ----
    const float bias = b1s[n0 + lm];
#pragma unroll
    for (int ii = 0; ii < 4; ++ii) {
        // C/D layout: col=lane&15, row=q*4+reg
        Hs[q * 4 + ii][n0 + lm] = fmaxf(acc[ii] + bias, 0.f);
    }
    __syncthreads();

    // ---- layer 2 + log_softmax: one wave per row, float4 per lane ----
    const int er = tid >> 6;   // row 0..15
    const int el = tid & 63;   // col-group: cols el*4 .. el*4+3

    const float4 h = *(const float4*)&Hs[er][el * 4];

    float part[10];
#pragma unroll
    for (int j = 0; j < 10; ++j) {
        const float4 w = *(const float4*)&W2s[j * 256 + el * 4];
        part[j] = h.x * w.x + h.y * w.y + h.z * w.z + h.w * w.w;
    }
#pragma unroll
    for (int mask = 1; mask < 64; mask <<= 1) {
#pragma unroll
        for (int j = 0; j < 10; ++j) part[j] += __shfl_xor(part[j], mask, 64);
    }

    float lg[10];
#pragma unroll
    for (int j = 0; j < 10; ++j) lg[j] = part[j] + b2s[j];
    float m = lg[0];
#pragma unroll
    for (int j = 1; j < 10; ++j) m = fmaxf(m, lg[j]);
    float se = 0.f;
#pragma unroll
    for (int j = 0; j < 10; ++j) se += expf(lg[j] - m);
    const float lse = m + logf(se);

    if (el < 10) out[(size_t)(r0 + er) * 10 + el] = lg[el] - lse;
}

// ---------------------------------------------------------------------------

extern "C" void kernel_launch(void* const* d_in, const int* in_sizes, int n_in,
                              void* d_out, int out_size, void* d_ws, size_t ws_size,
                              hipStream_t stream) {
    const float* x   = (const float*)d_in[0];  // [B,1,28,28]
    const float* var = (const float*)d_in[1];  // [2,4]
    const float* W1  = (const float*)d_in[2];  // [256,784]
    const float* b1  = (const float*)d_in[3];  // [256]
    const float* W2  = (const float*)d_in[4];  // [10,256]
    const float* b2  = (const float*)d_in[5];  // [10]
    float* out = (float*)d_out;                // [B,10]

    const int B = in_sizes[0] / 784;           // 4096

    unsigned short* w1bf = (unsigned short*)d_ws;  // [256,800] bf16

    w1cvt_kernel<<<(256 * KP) / 256, 256, 0, stream>>>(W1, w1bf);
    fused_kernel<<<B / 16, 1024, 0, stream>>>(x, var, w1bf, b1, W2, b2, out);
}